// Round 1
// baseline (557.299 us; speedup 1.0000x reference)
//
#include <hip/hip_runtime.h>
#include <cmath>

#define Bsz 4
#define Ssz 2048
#define Dsz 512
#define Hn 8
#define HDim 64
#define NEGBIG 1e9f

// C[M,N] = relu(A[M,K] @ W[K,N] + bias[N]); M,N,K multiples of 64/16, no bounds checks.
__global__ __launch_bounds__(256) void gemm_bias_relu_k(
    const float* __restrict__ A, const float* __restrict__ W,
    const float* __restrict__ bias, float* __restrict__ C,
    int M, int N, int K)
{
    __shared__ float As[64][17];   // [m][k], pad to keep stores ~2-way
    __shared__ float Bs[16][64];   // [k][n]
    const int tid = threadIdx.x;
    const int tr = tid >> 4, tc = tid & 15;
    const int row0 = blockIdx.y * 64, col0 = blockIdx.x * 64;
    float acc[4][4] = {};
    for (int k0 = 0; k0 < K; k0 += 16) {
#pragma unroll
        for (int i = 0; i < 4; i++) {
            int e = tid + i * 256;
            int m = e >> 4, kk = e & 15;
            As[m][kk] = A[(size_t)(row0 + m) * K + k0 + kk];
        }
#pragma unroll
        for (int i = 0; i < 4; i++) {
            int e = tid + i * 256;
            int kk = e >> 6, n = e & 63;
            Bs[kk][n] = W[(size_t)(k0 + kk) * N + col0 + n];
        }
        __syncthreads();
#pragma unroll
        for (int kk = 0; kk < 16; kk++) {
            float ra[4], rb[4];
#pragma unroll
            for (int i = 0; i < 4; i++) ra[i] = As[tr * 4 + i][kk];
#pragma unroll
            for (int j = 0; j < 4; j++) rb[j] = Bs[kk][tc * 4 + j];
#pragma unroll
            for (int i = 0; i < 4; i++)
#pragma unroll
                for (int j = 0; j < 4; j++)
                    acc[i][j] = fmaf(ra[i], rb[j], acc[i][j]);
        }
        __syncthreads();
    }
#pragma unroll
    for (int i = 0; i < 4; i++) {
        size_t r = (size_t)row0 + tr * 4 + i;
#pragma unroll
        for (int j = 0; j < 4; j++) {
            int c = col0 + tc * 4 + j;
            float v = acc[i][j] + bias[c];
            C[r * N + c] = fmaxf(v, 0.f);
        }
    }
}

// Flash-style attention with group (block-diagonal) masking.
// One block per (q-tile of 64, head, batch). 256 threads, 4x4 register tile each.
__global__ __launch_bounds__(256) void attn_k(
    const float* __restrict__ Q, const float* __restrict__ Kp,
    const float* __restrict__ V, const int* __restrict__ G,
    float* __restrict__ Y)
{
    __shared__ float Qs[64][65];   // [row][dim]
    __shared__ float KPs[64][65];  // K-tile transposed [dim][key]; reused as P [row][key]
    __shared__ float Vs[64][65];   // [key][dim]
    __shared__ int gq_s[64], gk_s[64];

    const int qt = blockIdx.x, h = blockIdx.y, b = blockIdx.z;
    const int q0 = qt * 64;
    const int tid = threadIdx.x;
    const int tr = tid >> 4, tc = tid & 15;

    const float* Qb = Q + (size_t)b * Ssz * Dsz + h * HDim;
    const float* Kb = Kp + (size_t)b * Ssz * Dsz + h * HDim;
    const float* Vb = V + (size_t)b * Ssz * Dsz + h * HDim;
    const int* Gb = G + (size_t)b * Ssz;

#pragma unroll
    for (int i = 0; i < 16; i++) {
        int e = tid + i * 256;
        int r = e >> 6, d = e & 63;
        Qs[r][d] = Qb[(size_t)(q0 + r) * Dsz + d];
    }
    if (tid < 64) gq_s[tid] = Gb[q0 + tid];
    __syncthreads();

    const int gqmin = gq_s[0], gqmax = gq_s[63]; // sorted groups
    int gq_r[4];
#pragma unroll
    for (int i = 0; i < 4; i++) gq_r[i] = gq_s[tr * 4 + i];

    float m_i[4], l_i[4], o[4][4];
#pragma unroll
    for (int i = 0; i < 4; i++) {
        m_i[i] = -INFINITY; l_i[i] = 0.f;
#pragma unroll
        for (int j = 0; j < 4; j++) o[i][j] = 0.f;
    }

    for (int kt = 0; kt < Ssz / 64; kt++) {
        int k0 = kt * 64;
        int gkf = Gb[k0], gkl = Gb[k0 + 63];
        if (gkl < gqmin || gkf > gqmax) continue;  // uniform skip: tile fully masked

#pragma unroll
        for (int i = 0; i < 16; i++) {
            int e = tid + i * 256;
            int r = e >> 6, d = e & 63;
            KPs[d][r] = Kb[(size_t)(k0 + r) * Dsz + d];
            Vs[r][d]  = Vb[(size_t)(k0 + r) * Dsz + d];
        }
        if (tid < 64) gk_s[tid] = Gb[k0 + tid];
        __syncthreads();

        float s[4][4];
#pragma unroll
        for (int i = 0; i < 4; i++)
#pragma unroll
            for (int j = 0; j < 4; j++) s[i][j] = 0.f;
        for (int d = 0; d < 64; d++) {
            float ra[4], rb[4];
#pragma unroll
            for (int i = 0; i < 4; i++) ra[i] = Qs[tr * 4 + i][d];
#pragma unroll
            for (int j = 0; j < 4; j++) rb[j] = KPs[d][tc * 4 + j];
#pragma unroll
            for (int i = 0; i < 4; i++)
#pragma unroll
                for (int j = 0; j < 4; j++)
                    s[i][j] = fmaf(ra[i], rb[j], s[i][j]);
        }
        int gk_r[4];
#pragma unroll
        for (int j = 0; j < 4; j++) gk_r[j] = gk_s[tc * 4 + j];
        const float scale = 0.125f;  // 1/sqrt(HD=64)
#pragma unroll
        for (int i = 0; i < 4; i++)
#pragma unroll
            for (int j = 0; j < 4; j++) {
                float sv = s[i][j] * scale;
                if (gq_r[i] != gk_r[j]) sv -= NEGBIG;
                s[i][j] = sv;
            }
        // online softmax; row owners are 16 consecutive tids within one wave
        float alpha[4];
#pragma unroll
        for (int i = 0; i < 4; i++) {
            float tmax = fmaxf(fmaxf(s[i][0], s[i][1]), fmaxf(s[i][2], s[i][3]));
#pragma unroll
            for (int off = 1; off < 16; off <<= 1)
                tmax = fmaxf(tmax, __shfl_xor(tmax, off, 16));
            float mn = fmaxf(m_i[i], tmax);
            alpha[i] = __expf(m_i[i] - mn);  // exp(-inf)=0 on first tile
            float rs = 0.f;
#pragma unroll
            for (int j = 0; j < 4; j++) {
                s[i][j] = __expf(s[i][j] - mn);
                rs += s[i][j];
            }
#pragma unroll
            for (int off = 1; off < 16; off <<= 1)
                rs += __shfl_xor(rs, off, 16);
            l_i[i] = l_i[i] * alpha[i] + rs;
            m_i[i] = mn;
#pragma unroll
            for (int j = 0; j < 4; j++) o[i][j] *= alpha[i];
        }
        __syncthreads();  // done reading KPs as K^T
#pragma unroll
        for (int i = 0; i < 4; i++)
#pragma unroll
            for (int j = 0; j < 4; j++)
                KPs[tr * 4 + i][tc * 4 + j] = s[i][j];  // P tile
        __syncthreads();
        for (int kk = 0; kk < 64; kk++) {
            float rp[4], rv[4];
#pragma unroll
            for (int i = 0; i < 4; i++) rp[i] = KPs[tr * 4 + i][kk];
#pragma unroll
            for (int j = 0; j < 4; j++) rv[j] = Vs[kk][tc * 4 + j];
#pragma unroll
            for (int i = 0; i < 4; i++)
#pragma unroll
                for (int j = 0; j < 4; j++)
                    o[i][j] = fmaf(rp[i], rv[j], o[i][j]);
        }
        __syncthreads();  // protect next tile's LDS loads
    }

#pragma unroll
    for (int i = 0; i < 4; i++) {
        float inv = 1.f / l_i[i];
        size_t row = (size_t)b * Ssz + q0 + tr * 4 + i;
#pragma unroll
        for (int j = 0; j < 4; j++)
            Y[row * Dsz + h * HDim + tc * 4 + j] = o[i][j] * inv;
    }
}

extern "C" void kernel_launch(void* const* d_in, const int* in_sizes, int n_in,
                              void* d_out, int out_size, void* d_ws, size_t ws_size,
                              hipStream_t stream)
{
    const float* x  = (const float*)d_in[0];
    const int*   g  = (const int*)d_in[1];
    const float* Wq = (const float*)d_in[2];
    const float* bq = (const float*)d_in[3];
    const float* Wk = (const float*)d_in[4];
    const float* bk = (const float*)d_in[5];
    const float* Wv = (const float*)d_in[6];
    const float* bv = (const float*)d_in[7];
    const float* Wo = (const float*)d_in[8];
    const float* bo = (const float*)d_in[9];
    float* out = (float*)d_out;

    const size_t elems = (size_t)Bsz * Ssz * Dsz; // 4M floats = 16 MB
    float* q = (float*)d_ws;
    float* k = q + elems;
    float* v = k + elems;
    float* y = v + elems;

    dim3 gb(Dsz / 64, (Bsz * Ssz) / 64);  // (8, 128)
    gemm_bias_relu_k<<<gb, 256, 0, stream>>>(x, Wq, bq, q, Bsz * Ssz, Dsz, Dsz);
    gemm_bias_relu_k<<<gb, 256, 0, stream>>>(x, Wk, bk, k, Bsz * Ssz, Dsz, Dsz);
    gemm_bias_relu_k<<<gb, 256, 0, stream>>>(x, Wv, bv, v, Bsz * Ssz, Dsz, Dsz);
    attn_k<<<dim3(Ssz / 64, Hn, Bsz), 256, 0, stream>>>(q, k, v, g, y);
    gemm_bias_relu_k<<<gb, 256, 0, stream>>>(y, Wo, bo, out, Bsz * Ssz, Dsz, Dsz);
}

// Round 2
// 177.614 us; speedup vs baseline: 3.1377x; 3.1377x over previous
//
#include <hip/hip_runtime.h>
#include <cmath>

#define Bsz 4
#define Ssz 2048
#define Dsz 512
#define Hn 8

typedef unsigned short u16;
typedef __attribute__((ext_vector_type(8))) short bf16x8;
typedef __attribute__((ext_vector_type(8))) unsigned short us8;
typedef __attribute__((ext_vector_type(4))) float f32x4;

__device__ __forceinline__ u16 f2bf(float f) {
    unsigned int u = __float_as_uint(f);
    u += 0x7fffu + ((u >> 16) & 1u);   // round-to-nearest-even
    return (u16)(u >> 16);
}

__device__ __forceinline__ void gl2lds16(const void* g, void* l) {
    __builtin_amdgcn_global_load_lds(
        (const __attribute__((address_space(1))) void*)g,
        (__attribute__((address_space(3))) void*)l, 16, 0, 0);
}

// ---- fp32 -> bf16 bulk convert (x) ----
__global__ __launch_bounds__(256) void conv_x(const float* __restrict__ x,
                                              u16* __restrict__ xb) {
    int i = blockIdx.x * 256 + threadIdx.x;   // one float4 per thread
    const float4* xv = (const float4*)x;
    float4 v = xv[i];
    u16* o = xb + (size_t)i * 4;
    o[0] = f2bf(v.x); o[1] = f2bf(v.y); o[2] = f2bf(v.z); o[3] = f2bf(v.w);
}

// ---- transpose+convert the 4 weight matrices: Wt[n][k] = W[k][n] (bf16) ----
__global__ __launch_bounds__(256) void conv_w(const float* __restrict__ Wq,
                                              const float* __restrict__ Wk,
                                              const float* __restrict__ Wv,
                                              const float* __restrict__ Wo,
                                              u16* __restrict__ Wtqkv,
                                              u16* __restrict__ Wto) {
    __shared__ float T[64][65];
    const int z = blockIdx.z;
    const float* W = (z == 0) ? Wq : (z == 1) ? Wk : (z == 2) ? Wv : Wo;
    const int n0 = blockIdx.x * 64, k0 = blockIdx.y * 64;
    const int tid = threadIdx.x;
#pragma unroll
    for (int i = 0; i < 16; i++) {
        int e = tid + i * 256;
        int r = e >> 6, c = e & 63;
        T[r][c] = W[(size_t)(k0 + r) * Dsz + n0 + c];
    }
    __syncthreads();
    u16* dst = (z < 3) ? (Wtqkv + ((size_t)z * 512 + n0) * Dsz + k0)
                       : (Wto + (size_t)n0 * Dsz + k0);
#pragma unroll
    for (int i = 0; i < 16; i++) {
        int e = tid + i * 256;
        int r = e >> 6, c = e & 63;
        dst[(size_t)r * Dsz + c] = f2bf(T[c][r]);
    }
}

// ---- 128x128-tile bf16 MFMA GEMM: C = relu(A @ Bt^T + bias) ----
// A [M,512] bf16 row-major; Bt [N,512] bf16 (= W^T). K=512 fixed, BK=64.
// MODE 0: bf16 out, 3-way column select (fused QKV). MODE 1: fp32 out.
template <int MODE>
__global__ __launch_bounds__(256) void gemm128(
    const u16* __restrict__ A, const u16* __restrict__ Bt,
    u16* o0, u16* o1, u16* o2,
    const float* b0, const float* b1, const float* b2,
    float* ofp, const float* bias_f) {
    __shared__ __align__(16) u16 As[128 * 64];
    __shared__ __align__(16) u16 Bs[128 * 64];
    const int tid = threadIdx.x;
    const int colg0 = blockIdx.x * 128;
    const int row0 = blockIdx.y * 128;
    const int w = tid >> 6, lane = tid & 63;
    const int ln = lane & 15, quad = lane >> 4;
    const int wr = w >> 1, wc = w & 1;

    f32x4 acc[4][4];
    const f32x4 z4 = {0.f, 0.f, 0.f, 0.f};
#pragma unroll
    for (int bi = 0; bi < 4; bi++)
#pragma unroll
        for (int bj = 0; bj < 4; bj++) acc[bi][bj] = z4;

    const u16* Ablk = A + (size_t)row0 * 512;
    const u16* Bblk = Bt + (size_t)colg0 * 512;

    for (int k0 = 0; k0 < 512; k0 += 64) {
        __syncthreads();
#pragma unroll
        for (int i = 0; i < 4; i++) {
            int p = tid + i * 256;           // chunk id, 16B each
            int m = p >> 3, kc = p & 7;
            int gk = ((kc ^ (m & 7)) << 3);  // XOR-swizzled k origin
            gl2lds16(Ablk + (size_t)m * 512 + k0 + gk, As + p * 8);
            gl2lds16(Bblk + (size_t)m * 512 + k0 + gk, Bs + p * 8);
        }
        __syncthreads();
#pragma unroll
        for (int kk2 = 0; kk2 < 2; kk2++) {
            bf16x8 af[4], bfr[4];
#pragma unroll
            for (int bi = 0; bi < 4; bi++) {
                int r = wr * 64 + bi * 16 + ln;
                int ch = r * 8 + ((kk2 * 4 + quad) ^ (r & 7));
                af[bi] = *(const bf16x8*)(As + ch * 8);
            }
#pragma unroll
            for (int bj = 0; bj < 4; bj++) {
                int n = wc * 64 + bj * 16 + ln;
                int ch = n * 8 + ((kk2 * 4 + quad) ^ (n & 7));
                bfr[bj] = *(const bf16x8*)(Bs + ch * 8);
            }
#pragma unroll
            for (int bi = 0; bi < 4; bi++)
#pragma unroll
                for (int bj = 0; bj < 4; bj++)
                    acc[bi][bj] = __builtin_amdgcn_mfma_f32_16x16x32_bf16(
                        af[bi], bfr[bj], acc[bi][bj], 0, 0, 0);
        }
    }

    if (MODE == 0) {
        const int sel = colg0 >> 9;        // 128-tiles never straddle a 512 boundary
        const int c0 = colg0 & 511;
        u16* outp = (sel == 0) ? o0 : (sel == 1) ? o1 : o2;
        const float* bp = (sel == 0) ? b0 : (sel == 1) ? b1 : b2;
#pragma unroll
        for (int bj = 0; bj < 4; bj++) {
            int col = c0 + wc * 64 + bj * 16 + ln;
            float bv = bp[col];
#pragma unroll
            for (int bi = 0; bi < 4; bi++)
#pragma unroll
                for (int r = 0; r < 4; r++) {
                    int row = row0 + wr * 64 + bi * 16 + quad * 4 + r;
                    float v = acc[bi][bj][r] + bv;
                    outp[(size_t)row * 512 + col] = f2bf(fmaxf(v, 0.f));
                }
        }
    } else {
#pragma unroll
        for (int bj = 0; bj < 4; bj++) {
            int col = colg0 + wc * 64 + bj * 16 + ln;
            float bv = bias_f[col];
#pragma unroll
            for (int bi = 0; bi < 4; bi++)
#pragma unroll
                for (int r = 0; r < 4; r++) {
                    int row = row0 + wr * 64 + bi * 16 + quad * 4 + r;
                    ofp[(size_t)row * 512 + col] = fmaxf(acc[bi][bj][r] + bv, 0.f);
                }
        }
    }
}

// ---- MFMA flash attention with block-diagonal group mask ----
// Block: 64 q-rows (4 waves x 16), iterate 64-key tiles with group skip.
__global__ __launch_bounds__(256) void attn_mfma(
    const u16* __restrict__ Q, const u16* __restrict__ Kg,
    const u16* __restrict__ V, const int* __restrict__ G,
    u16* __restrict__ Y) {
    __shared__ __align__(16) u16 Qs[64 * 64];   // swizzled chunks
    __shared__ __align__(16) u16 Ks[64 * 64];   // swizzled chunks
    __shared__ __align__(16) u16 Vt[64 * 72];   // V^T [d][key], +8 pad
    __shared__ __align__(16) u16 Ps[64 * 72];   // P [q][key], +8 pad
    __shared__ int gq_s[64];
    __shared__ int gk_s[64];

    const int qt = blockIdx.x, h = blockIdx.y, b = blockIdx.z;
    const int q0 = qt * 64;
    const int tid = threadIdx.x;
    const int w = tid >> 6, lane = tid & 63;
    const int ln = lane & 15, quad = lane >> 4;

    const size_t base = (size_t)b * Ssz * Dsz;
    const u16* Qb = Q + base;
    const u16* Kb = Kg + base;
    const u16* Vb = V + base;
    const int* Gb = G + (size_t)b * Ssz;

#pragma unroll
    for (int i = 0; i < 2; i++) {
        int p = tid + i * 256;
        int m = p >> 3, kc = p & 7;
        int gk = ((kc ^ (m & 7)) << 3);
        gl2lds16(Qb + (size_t)(q0 + m) * Dsz + h * 64 + gk, Qs + p * 8);
    }
    if (tid < 64) gq_s[tid] = Gb[q0 + tid];
    __syncthreads();

    const int gqmin = gq_s[0], gqmax = gq_s[63];
    int gq_r[4];
#pragma unroll
    for (int r = 0; r < 4; r++) gq_r[r] = gq_s[w * 16 + quad * 4 + r];

    // hoist Q A-fragments (constant per block)
    bf16x8 qf[2];
#pragma unroll
    for (int kh = 0; kh < 2; kh++) {
        int rr = w * 16 + ln;
        int ch = rr * 8 + ((kh * 4 + quad) ^ (rr & 7));
        qf[kh] = *(const bf16x8*)(Qs + ch * 8);
    }

    float m_i[4], l_i[4];
    f32x4 o[4];
    const f32x4 z4 = {0.f, 0.f, 0.f, 0.f};
#pragma unroll
    for (int r = 0; r < 4; r++) { m_i[r] = -INFINITY; l_i[r] = 0.f; }
#pragma unroll
    for (int nd = 0; nd < 4; nd++) o[nd] = z4;

    for (int kt = 0; kt < Ssz / 64; kt++) {
        const int k0 = kt * 64;
        const int gkf = Gb[k0], gkl = Gb[k0 + 63];
        if (gkf > gqmax) break;       // groups sorted: nothing later overlaps
        if (gkl < gqmin) continue;    // tile fully masked
        __syncthreads();              // previous tile's LDS reads complete

#pragma unroll
        for (int i = 0; i < 2; i++) {
            int p = tid + i * 256;
            int m = p >> 3, kc = p & 7;
            int gkx = ((kc ^ (m & 7)) << 3);
            gl2lds16(Kb + (size_t)(k0 + m) * Dsz + h * 64 + gkx, Ks + p * 8);
        }
#pragma unroll
        for (int pass = 0; pass < 2; pass++) {   // V^T staging
            int c = pass * 256 + tid;
            int key = c & 63, d0 = (c >> 6) * 8;
            us8 v8 = *(const us8*)(Vb + (size_t)(k0 + key) * Dsz + h * 64 + d0);
#pragma unroll
            for (int j = 0; j < 8; j++) Vt[(d0 + j) * 72 + key] = v8[j];
        }
        if (tid < 64) gk_s[tid] = Gb[k0 + tid];
        __syncthreads();

        // S = Q K^T (C/D layout: row=quad*4+r, col=nb*16+ln)
        f32x4 sb[4];
#pragma unroll
        for (int nb = 0; nb < 4; nb++) {
            f32x4 s = z4;
#pragma unroll
            for (int kh = 0; kh < 2; kh++) {
                int rr = nb * 16 + ln;
                int ch = rr * 8 + ((kh * 4 + quad) ^ (rr & 7));
                bf16x8 kf = *(const bf16x8*)(Ks + ch * 8);
                s = __builtin_amdgcn_mfma_f32_16x16x32_bf16(qf[kh], kf, s, 0, 0, 0);
            }
            sb[nb] = s;
        }
        int gk_c[4];
#pragma unroll
        for (int nb = 0; nb < 4; nb++) gk_c[nb] = gk_s[nb * 16 + ln];

#pragma unroll
        for (int r = 0; r < 4; r++) {
            float sv[4];
#pragma unroll
            for (int nb = 0; nb < 4; nb++)
                sv[nb] = sb[nb][r] * 0.125f + ((gq_r[r] == gk_c[nb]) ? 0.f : -1e9f);
            float tm = fmaxf(fmaxf(sv[0], sv[1]), fmaxf(sv[2], sv[3]));
#pragma unroll
            for (int off = 1; off < 16; off <<= 1)
                tm = fmaxf(tm, __shfl_xor(tm, off, 16));
            float mn = fmaxf(m_i[r], tm);
            float alpha = __expf(m_i[r] - mn);   // exp(-inf)=0 on first tile
            m_i[r] = mn;
            float rs = 0.f;
#pragma unroll
            for (int nb = 0; nb < 4; nb++) { sv[nb] = __expf(sv[nb] - mn); rs += sv[nb]; }
#pragma unroll
            for (int off = 1; off < 16; off <<= 1)
                rs += __shfl_xor(rs, off, 16);
            l_i[r] = l_i[r] * alpha + rs;
#pragma unroll
            for (int nd = 0; nd < 4; nd++) o[nd][r] *= alpha;
            int prow = w * 16 + quad * 4 + r;
#pragma unroll
            for (int nb = 0; nb < 4; nb++)
                Ps[prow * 72 + nb * 16 + ln] = f2bf(sv[nb]);
        }
        __syncthreads();   // P visible (and cheap cross-wave safety)

        // O += P V^T : A-operand = P[q=ln][k], B-operand = Vt[d=ln][k]
        bf16x8 pf[2];
#pragma unroll
        for (int kh = 0; kh < 2; kh++)
            pf[kh] = *(const bf16x8*)(Ps + (w * 16 + ln) * 72 + kh * 32 + quad * 8);
#pragma unroll
        for (int nd = 0; nd < 4; nd++) {
#pragma unroll
            for (int kh = 0; kh < 2; kh++) {
                bf16x8 vf = *(const bf16x8*)(Vt + (nd * 16 + ln) * 72 + kh * 32 + quad * 8);
                o[nd] = __builtin_amdgcn_mfma_f32_16x16x32_bf16(pf[kh], vf, o[nd], 0, 0, 0);
            }
        }
    }

#pragma unroll
    for (int r = 0; r < 4; r++) {
        float inv = 1.f / l_i[r];
        size_t row = (size_t)b * Ssz + q0 + w * 16 + quad * 4 + r;
#pragma unroll
        for (int nd = 0; nd < 4; nd++)
            Y[row * Dsz + h * 64 + nd * 16 + ln] = f2bf(o[nd][r] * inv);
    }
}

extern "C" void kernel_launch(void* const* d_in, const int* in_sizes, int n_in,
                              void* d_out, int out_size, void* d_ws, size_t ws_size,
                              hipStream_t stream) {
    const float* x  = (const float*)d_in[0];
    const int*   g  = (const int*)d_in[1];
    const float* Wq = (const float*)d_in[2];
    const float* bq = (const float*)d_in[3];
    const float* Wk = (const float*)d_in[4];
    const float* bk = (const float*)d_in[5];
    const float* Wv = (const float*)d_in[6];
    const float* bv = (const float*)d_in[7];
    const float* Wo = (const float*)d_in[8];
    const float* bo = (const float*)d_in[9];
    float* out = (float*)d_out;

    const size_t E = (size_t)Bsz * Ssz * Dsz;   // 4M elements
    u16* ws = (u16*)d_ws;
    u16* xb = ws;
    u16* qb = xb + E;
    u16* kb = qb + E;
    u16* vb = kb + E;
    u16* yb = vb + E;
    u16* Wtqkv = yb + E;                 // [1536][512]
    u16* Wto   = Wtqkv + 1536 * 512;     // [512][512]

    conv_x<<<4096, 256, 0, stream>>>(x, xb);
    conv_w<<<dim3(8, 8, 4), 256, 0, stream>>>(Wq, Wk, Wv, Wo, Wtqkv, Wto);
    gemm128<0><<<dim3(12, 64), 256, 0, stream>>>(xb, Wtqkv, qb, kb, vb,
                                                 bq, bk, bv, nullptr, nullptr);
    attn_mfma<<<dim3(Ssz / 64, Hn, Bsz), 256, 0, stream>>>(qb, kb, vb, g, yb);
    gemm128<1><<<dim3(4, 64), 256, 0, stream>>>(yb, Wto, nullptr, nullptr, nullptr,
                                                nullptr, nullptr, nullptr, out, bo);
}